// Round 14
// baseline (36.094 us; speedup 1.0000x reference)
//
#include <hip/hip_runtime.h>
#include <math.h>

#define HW_   6688      // 44*152
#define W_    152
#define NPIX  107008    // 16*44*152
#define OW_   1216      // 152*8
#define OHW_  428032    // 352*1216

typedef _Float16 f16;
typedef _Float16 f16x2 __attribute__((ext_vector_type(2)));
typedef _Float16 f16x4 __attribute__((ext_vector_type(4)));
typedef _Float16 f16x8 __attribute__((ext_vector_type(8)));
typedef float    f32x4 __attribute__((ext_vector_type(4)));

#define MFMA(a,b,c) __builtin_amdgcn_mfma_f32_16x16x32_f16((a),(b),(c),0,0,0)

// ---- LDS layout (f16 units): activation buffers ONLY (x never staged).
// All buffers disjoint; each wave touches only its own 32 rows -> no block
// barriers anywhere, only intra-wave fences.
#define SA0_OFF  0              // a0 [128][72] -> 9216
#define SA0_STR  72
#define SA1_OFF  9216           // a1 [128][40] -> 14336
#define SA1_STR  40
#define SA2_OFF  14336          // a2 [128][24] -> 17408
#define SA2_STR  24
#define SA3_OFF  17408          // a3 [128][16] -> 19456
#define SA3_STR  16
#define LDSF16   19456          // 38912 B -> 4 blocks/CU

__device__ __forceinline__ float fast_sigmoid(float v) {
    return __builtin_amdgcn_rcpf(1.0f + __expf(-v));
}
__device__ __forceinline__ float eluf(float v) {
    return v > 0.0f ? v : (__expf(v) - 1.0f);
}
// split fp32 -> fp16 hi + fp16 lo (w ~= hi + lo)
__device__ __forceinline__ void split8(const float* v, f16x8& hi, f16x8& lo) {
#pragma unroll
    for (int e = 0; e < 8; ++e) {
        f16 h = (f16)v[e];
        hi[e] = h;
        lo[e] = (f16)(v[e] - (float)h);
    }
}
__device__ __forceinline__ f16x8 cvt8(const float* v) {
    f16x8 r;
#pragma unroll
    for (int e = 0; e < 8; e += 2) {
        auto pk = __builtin_amdgcn_cvt_pkrtz(v[e], v[e + 1]);
        r[e] = (f16)pk[0]; r[e + 1] = (f16)pk[1];
    }
    return r;
}
__device__ __forceinline__ f16x4 elu_cvt4(f32x4 a) {
    f16x4 r;
    r[0] = (f16)eluf(a[0]); r[1] = (f16)eluf(a[1]);
    r[2] = (f16)eluf(a[2]); r[3] = (f16)eluf(a[3]);
    return r;
}
// Intra-wave LDS handoff fence (cross-wave safety = disjoint rows/regions).
__device__ __forceinline__ void wave_fence() {
    __builtin_amdgcn_sched_barrier(0);
    __builtin_amdgcn_wave_barrier();
    __builtin_amdgcn_sched_barrier(0);
}

// 256 threads = 4 waves, 128 pixels/block; wave wv owns pixels wv*32..+31
// END-TO-END. Layer 0: x B-frags gathered straight from global to registers
// (kt-pipelined), full w0 streamed from L2 per wave (hot). ZERO __syncthreads;
// all LDS handoffs are intra-wave, fenced with wave_fence().
__global__ __launch_bounds__(256, 4)
void lpg_mfma(const float* __restrict__ x,
              const float* __restrict__ w0, const float* __restrict__ b0,
              const float* __restrict__ w1, const float* __restrict__ b1,
              const float* __restrict__ w2, const float* __restrict__ b2,
              const float* __restrict__ w3, const float* __restrict__ b3,
              const float* __restrict__ w4, const float* __restrict__ b4,
              const float* __restrict__ cw, const float* __restrict__ cb,
              float* __restrict__ out) {
    __shared__ __align__(16) f16 S[LDSF16];

    const int tid  = threadIdx.x;
    const int wv   = __builtin_amdgcn_readfirstlane(tid >> 6);
    const int lane = tid & 63;
    const int p    = lane & 15;   // MFMA row/col index
    const int q    = lane >> 4;   // k-group / C-row group
    const int pixbase = blockIdx.x * 128;

    const int i0a = wv * 32 + p;        // tile A block-local row
    const int i0b = wv * 32 + 16 + p;   // tile B

    // per-lane x gather bases (channel q*8, own pixels)
    const int pixA = pixbase + i0a;
    const int pixB = pixbase + i0b;
    const int bbA = pixA / HW_, hwA = pixA - bbA * HW_;
    const int bbB = pixB / HW_, hwB = pixB - bbB * HW_;
    const float* xA = x + ((size_t)bbA * 128 + q * 8) * HW_ + hwA;
    const float* xB = x + ((size_t)bbB * 128 + q * 8) * HW_ + hwB;

    // ---- layer 0: 128 -> 64, all 4 M-tiles, own 2 pixel tiles ----
    f32x4 acc[4][2];
#pragma unroll
    for (int Mt = 0; Mt < 4; ++Mt) {
        f32x4 b0v = *(const f32x4*)(b0 + Mt * 16 + 4 * q);
        acc[Mt][0] = b0v; acc[Mt][1] = b0v;
    }

    float vA[2][8], vB[2][8];
#pragma unroll
    for (int e = 0; e < 8; ++e) {       // prefetch kt=0
        vA[0][e] = xA[(size_t)e * HW_];
        vB[0][e] = xB[(size_t)e * HW_];
    }
#pragma unroll
    for (int kt = 0; kt < 4; ++kt) {
        const int cur = kt & 1, nxt = cur ^ 1;
        if (kt < 3) {                   // prefetch kt+1 (hidden under MFMAs)
#pragma unroll
            for (int e = 0; e < 8; ++e) {
                vA[nxt][e] = xA[(size_t)((kt + 1) * 32 + e) * HW_];
                vB[nxt][e] = xB[(size_t)((kt + 1) * 32 + e) * HW_];
            }
        }
        f16x8 bfA = cvt8(vA[cur]);
        f16x8 bfB = cvt8(vB[cur]);
#pragma unroll
        for (int Mt = 0; Mt < 4; ++Mt) {
            const float* wr = w0 + (Mt * 16 + p) * 128 + kt * 32 + q * 8;
            float w8[8];
#pragma unroll
            for (int e = 0; e < 8; ++e) w8[e] = wr[e];
            f16x8 wh, wl; split8(w8, wh, wl);
            acc[Mt][0] = MFMA(wh, bfA, acc[Mt][0]);
            acc[Mt][0] = MFMA(wl, bfA, acc[Mt][0]);
            acc[Mt][1] = MFMA(wh, bfB, acc[Mt][1]);
            acc[Mt][1] = MFMA(wl, bfB, acc[Mt][1]);
        }
    }
#pragma unroll
    for (int Mt = 0; Mt < 4; ++Mt) {
        *(f16x4*)(S + SA0_OFF + i0a * SA0_STR + Mt * 16 + 4 * q) = elu_cvt4(acc[Mt][0]);
        *(f16x4*)(S + SA0_OFF + i0b * SA0_STR + Mt * 16 + 4 * q) = elu_cvt4(acc[Mt][1]);
    }
    wave_fence();   // a0 handoff (intra-wave cross-lane)

    // ================= phase C: wave-private (fences only) =================
    f16x8 w1h[2][2], w1l[2][2];
#pragma unroll
    for (int Mt = 0; Mt < 2; ++Mt)
#pragma unroll
        for (int kt = 0; kt < 2; ++kt) {
            float v[8];
#pragma unroll
            for (int e = 0; e < 8; ++e) v[e] = w1[(Mt * 16 + p) * 64 + kt * 32 + q * 8 + e];
            split8(v, w1h[Mt][kt], w1l[Mt][kt]);
        }
    f16x8 w2h, w2l;
    {
        float v[8];
#pragma unroll
        for (int e = 0; e < 8; ++e) v[e] = w2[p * 32 + q * 8 + e];
        split8(v, w2h, w2l);
    }
    f16x8 w3h, w3l;
    {
        float v[8];
        bool ok = (p < 8) && (q < 2);
#pragma unroll
        for (int e = 0; e < 8; ++e) v[e] = ok ? w3[p * 16 + q * 8 + e] : 0.0f;
        split8(v, w3h, w3l);
    }
    f16x8 w4h, w4l;
    {
        float v[8];
        bool ok = (p < 4) && (q == 0);
#pragma unroll
        for (int e = 0; e < 8; ++e) v[e] = ok ? w4[p * 8 + e] : 0.0f;
        split8(v, w4h, w4l);
    }
    f16x8 whh, whl;
    {
        float v[8];
        bool ok = (p < 3) && (q == 0);
#pragma unroll
        for (int e = 0; e < 8; ++e) v[e] = (ok && e < 4) ? cw[p * 4 + e] : 0.0f;
        split8(v, whh, whl);
    }
    const f32x4 z4 = {0.f, 0.f, 0.f, 0.f};
    f32x4 b1v0 = *(const f32x4*)(b1 + 4 * q);
    f32x4 b1v1 = *(const f32x4*)(b1 + 16 + 4 * q);
    f32x4 b2v  = *(const f32x4*)(b2 + 4 * q);
    f32x4 b3v  = *(const f32x4*)(b3 + (q & 1) * 4);
    f32x4 b4v  = *(const f32x4*)(b4);
    float cb0v = cb[0], cb1v = cb[1], cb2v = cb[2];

    // ---- layer 1: 64 -> 32
    {
        f32x4 cA0 = b1v0, cA1 = b1v1, cB0 = b1v0, cB1 = b1v1;
#pragma unroll
        for (int kt = 0; kt < 2; ++kt) {
            f16x8 bfA = *(const f16x8*)(S + SA0_OFF + i0a * SA0_STR + kt * 32 + q * 8);
            f16x8 bfB = *(const f16x8*)(S + SA0_OFF + i0b * SA0_STR + kt * 32 + q * 8);
            cA0 = MFMA(w1h[0][kt], bfA, cA0); cA0 = MFMA(w1l[0][kt], bfA, cA0);
            cA1 = MFMA(w1h[1][kt], bfA, cA1); cA1 = MFMA(w1l[1][kt], bfA, cA1);
            cB0 = MFMA(w1h[0][kt], bfB, cB0); cB0 = MFMA(w1l[0][kt], bfB, cB0);
            cB1 = MFMA(w1h[1][kt], bfB, cB1); cB1 = MFMA(w1l[1][kt], bfB, cB1);
        }
        *(f16x4*)(S + SA1_OFF + i0a * SA1_STR + 4 * q)      = elu_cvt4(cA0);
        *(f16x4*)(S + SA1_OFF + i0a * SA1_STR + 16 + 4 * q) = elu_cvt4(cA1);
        *(f16x4*)(S + SA1_OFF + i0b * SA1_STR + 4 * q)      = elu_cvt4(cB0);
        *(f16x4*)(S + SA1_OFF + i0b * SA1_STR + 16 + 4 * q) = elu_cvt4(cB1);
    }
    wave_fence();   // a1 handoff

    // ---- layer 2: 32 -> 16
    {
        f16x8 bfA = *(const f16x8*)(S + SA1_OFF + i0a * SA1_STR + q * 8);
        f16x8 bfB = *(const f16x8*)(S + SA1_OFF + i0b * SA1_STR + q * 8);
        f32x4 cA = b2v, cB = b2v;
        cA = MFMA(w2h, bfA, cA); cA = MFMA(w2l, bfA, cA);
        cB = MFMA(w2h, bfB, cB); cB = MFMA(w2l, bfB, cB);
        *(f16x4*)(S + SA2_OFF + i0a * SA2_STR + 4 * q) = elu_cvt4(cA);
        *(f16x4*)(S + SA2_OFF + i0b * SA2_STR + 4 * q) = elu_cvt4(cB);
    }
    wave_fence();   // a2 handoff

    // ---- layer 3: 16 -> 8 (K valid for q<2)
    {
        f16x8 bfA = *(const f16x8*)(S + SA2_OFF + i0a * SA2_STR + (q & 1) * 8);
        f16x8 bfB = *(const f16x8*)(S + SA2_OFF + i0b * SA2_STR + (q & 1) * 8);
        if (q >= 2) { bfA = (f16x8){}; bfB = (f16x8){}; }
        f32x4 cA = (q < 2) ? b3v : z4, cB = (q < 2) ? b3v : z4;
        cA = MFMA(w3h, bfA, cA); cA = MFMA(w3l, bfA, cA);
        cB = MFMA(w3h, bfB, cB); cB = MFMA(w3l, bfB, cB);
        if (q < 2) {
            *(f16x4*)(S + SA3_OFF + i0a * SA3_STR + 4 * q) = elu_cvt4(cA);
            *(f16x4*)(S + SA3_OFF + i0b * SA3_STR + 4 * q) = elu_cvt4(cB);
        }
    }
    wave_fence();   // a3 handoff

    // ---- layer 4 (8->4) + head (4->3): a4 stays in registers
    f32x4 cyA, cyB;
    {
        f16x8 bfA = *(const f16x8*)(S + SA3_OFF + i0a * SA3_STR);
        f16x8 bfB = *(const f16x8*)(S + SA3_OFF + i0b * SA3_STR);
        if (q != 0) { bfA = (f16x8){}; bfB = (f16x8){}; }
        f32x4 cA = (q == 0) ? b4v : z4, cB = (q == 0) ? b4v : z4;
        cA = MFMA(w4h, bfA, cA); cA = MFMA(w4l, bfA, cA);
        cB = MFMA(w4h, bfB, cB); cB = MFMA(w4l, bfB, cB);

        f16x8 hA = (f16x8){}, hB = (f16x8){};
        if (q == 0) {
#pragma unroll
            for (int e = 0; e < 4; ++e) {
                hA[e] = (f16)eluf(cA[e]);
                hB[e] = (f16)eluf(cB[e]);
            }
        }
        cyA = z4; cyB = z4;
        if (q == 0) {
            cyA[0] = cb0v; cyA[1] = cb1v; cyA[2] = cb2v;
            cyB[0] = cb0v; cyB[1] = cb1v; cyB[2] = cb2v;
        }
        cyA = MFMA(whh, hA, cyA); cyA = MFMA(whl, hA, cyA);
        cyB = MFMA(whh, hB, cyB); cyB = MFMA(whl, hB, cyB);
    }

    // ---- epilogue: y via shuffle from the q==0 lane of column p ----
#pragma unroll
    for (int nt = 0; nt < 2; ++nt) {
        const int i0 = wv * 32 + nt * 16 + p;
        float y0 = __shfl(nt ? cyB[0] : cyA[0], p);
        float y1 = __shfl(nt ? cyB[1] : cyA[1], p);
        float y2 = __shfl(nt ? cyB[2] : cyA[2], p);

        float theta = 0.5235987756f * fast_sigmoid(y0);   // pi/6
        float phi   = 6.2831853072f * fast_sigmoid(y1);   // 2*pi
        float dist  = 83.0f         * fast_sigmoid(y2);
        float st = __sinf(theta), ct = __cosf(theta);
        float sp = __sinf(phi),   cp = __cosf(phi);
        float n1 = st * cp, n2 = st * sp, n3 = ct;
        float inv = __frsqrt_rn(fmaf(n1, n1, fmaf(n2, n2, n3 * n3)));
        n1 *= inv; n2 *= inv; n3 *= inv;

        const float ksc = 1.0f / (8.0f * 715.0f);
        float nu[8];
#pragma unroll
        for (int j = 0; j < 8; ++j) nu[j] = n1 * (((float)j - 3.5f) * ksc);

        int pix = pixbase + i0;
        int bb  = pix / HW_;
        int hw  = pix - bb * HW_;
        int hh  = hw / W_;
        int ww  = hw - hh * W_;
        const int obase = bb * OHW_ + (hh * 8) * OW_ + ww * 8;
#pragma unroll
        for (int r = 0; r < 2; ++r) {
            int irow = q * 2 + r;               // lane (p,q) writes rows 2q,2q+1
            float base = fmaf(n2, ((float)irow - 3.5f) * ksc, n3);
            float4 r0, r1;
            r0.x = dist * __builtin_amdgcn_rcpf(base + nu[0]);
            r0.y = dist * __builtin_amdgcn_rcpf(base + nu[1]);
            r0.z = dist * __builtin_amdgcn_rcpf(base + nu[2]);
            r0.w = dist * __builtin_amdgcn_rcpf(base + nu[3]);
            r1.x = dist * __builtin_amdgcn_rcpf(base + nu[4]);
            r1.y = dist * __builtin_amdgcn_rcpf(base + nu[5]);
            r1.z = dist * __builtin_amdgcn_rcpf(base + nu[6]);
            r1.w = dist * __builtin_amdgcn_rcpf(base + nu[7]);
            float4* op = (float4*)(out + obase + irow * OW_);
            op[0] = r0;
            op[1] = r1;
        }
    }
}

extern "C" void kernel_launch(void* const* d_in, const int* in_sizes, int n_in,
                              void* d_out, int out_size, void* d_ws, size_t ws_size,
                              hipStream_t stream) {
    const float* x  = (const float*)d_in[0];
    const float* w0 = (const float*)d_in[1];
    const float* b0 = (const float*)d_in[2];
    const float* w1 = (const float*)d_in[3];
    const float* b1 = (const float*)d_in[4];
    const float* w2 = (const float*)d_in[5];
    const float* b2 = (const float*)d_in[6];
    const float* w3 = (const float*)d_in[7];
    const float* b3 = (const float*)d_in[8];
    const float* w4 = (const float*)d_in[9];
    const float* b4 = (const float*)d_in[10];
    const float* cw = (const float*)d_in[11];
    const float* cb = (const float*)d_in[12];
    float* outp = (float*)d_out;

    lpg_mfma<<<NPIX / 128, 256, 0, stream>>>(x, w0, b0, w1, b1, w2, b2, w3, b3,
                                             w4, b4, cw, cb, outp);
}